// Round 4
// baseline (44.626 us; speedup 1.0000x reference)
//
#include <hip/hip_runtime.h>
#include <math.h>

#define NPTS   4096
#define BATCH  8
#define NBD    (2 * BATCH)
#define BLOCK  256
#define PN     8                 // p points per thread
#define MCHUNK 256               // q points staged per block (128 pairs)
#define NTILE  (BLOCK * PN)      // 2048 n per block
#define NBLK   (NPTS / NTILE)    // 2
#define NCHUNK (NPTS / MCHUNK)   // 16

typedef float v2f __attribute__((ext_vector_type(2)));

static __device__ __forceinline__ v2f pk_fma(v2f a, v2f b, v2f c) {
  v2f d;
  asm("v_pk_fma_f32 %0, %1, %2, %3" : "=v"(d) : "v"(a), "v"(b), "v"(c));
  return d;
}

// Pass 1: per (bd, m-chunk, n-tile), partial min over the chunk of
// d2 = |p|^2 + (|q|^2 - 2 p.q); plain-store partials (no init, no atomics).
// bd = b*2 + dir. dir 0: p=x, q=y; dir 1: p=y, q=x.
__global__ __launch_bounds__(BLOCK) void partial_min_kernel(
    const float* __restrict__ x, const float* __restrict__ y,
    float* __restrict__ part) {
  const int bd  = blockIdx.z;
  const int b   = bd >> 1;
  const int dir = bd & 1;

  const float* __restrict__ P = (dir == 0) ? x : y;
  const float* __restrict__ Q = (dir == 0) ? y : x;
  const float* Pb = P + (size_t)b * NPTS * 3;
  const float* Qb = Q + (size_t)b * NPTS * 3 + (size_t)blockIdx.y * MCHUNK * 3;

  // Per q-pair (2 points): qA = (-2x0,-2x1,-2y0,-2y1), qB = (-2z0,-2z1,|q0|^2,|q1|^2)
  __shared__ float4 qA[MCHUNK / 2];
  __shared__ float4 qB[MCHUNK / 2];
  if (threadIdx.x < MCHUNK / 2) {
    const int t = threadIdx.x;
    const float x0 = Qb[6 * t + 0], y0 = Qb[6 * t + 1], z0 = Qb[6 * t + 2];
    const float x1 = Qb[6 * t + 3], y1 = Qb[6 * t + 4], z1 = Qb[6 * t + 5];
    qA[t] = make_float4(-2.0f * x0, -2.0f * x1, -2.0f * y0, -2.0f * y1);
    qB[t] = make_float4(-2.0f * z0, -2.0f * z1,
                        x0 * x0 + y0 * y0 + z0 * z0,
                        x1 * x1 + y1 * y1 + z1 * z1);
  }
  __syncthreads();

  const int n0 = blockIdx.x * NTILE + threadIdx.x;
  v2f px2[PN], py2[PN], pz2[PN];
  float p2[PN], mn[PN];
#pragma unroll
  for (int i = 0; i < PN; ++i) {
    const int n = n0 + i * BLOCK;
    const float px = Pb[3 * n + 0];
    const float py = Pb[3 * n + 1];
    const float pz = Pb[3 * n + 2];
    px2[i] = (v2f){px, px};
    py2[i] = (v2f){py, py};
    pz2[i] = (v2f){pz, pz};
    p2[i]  = px * px + py * py + pz * pz;
    mn[i]  = 3.4e38f;
  }

#pragma unroll 4
  for (int m = 0; m < MCHUNK / 2; ++m) {
    const float4 a = qA[m];  // uniform address -> broadcast ds_read_b128
    const float4 c = qB[m];
    const v2f qx = (v2f){a.x, a.y};
    const v2f qy = (v2f){a.z, a.w};
    const v2f qz = (v2f){c.x, c.y};
    const v2f qw = (v2f){c.z, c.w};
#pragma unroll
    for (int i = 0; i < PN; ++i) {
      v2f t = pk_fma(pz2[i], qz, qw);
      t = pk_fma(py2[i], qy, t);
      t = pk_fma(px2[i], qx, t);
      mn[i] = fminf(mn[i], fminf(t.x, t.y));  // -> v_min3_f32
    }
  }

  float* wp = part + ((size_t)bd * NCHUNK + blockIdx.y) * NPTS + n0;
#pragma unroll
  for (int i = 0; i < PN; ++i)
    wp[i * BLOCK] = mn[i] + p2[i];
}

// Pass 2: one block per bd; min across chunks per n (coalesced), max over n.
__global__ __launch_bounds__(1024) void reduce1_kernel(
    const float* __restrict__ part, float* __restrict__ bdmax) {
  const int bd = blockIdx.x;
  const float* base = part + (size_t)bd * NCHUNK * NPTS;

  float mx = 0.0f;
  for (int n = threadIdx.x; n < NPTS; n += 1024) {
    float mn = base[n];
#pragma unroll
    for (int c = 1; c < NCHUNK; ++c)
      mn = fminf(mn, base[(size_t)c * NPTS + n]);
    mx = fmaxf(mx, mn);
  }
  for (int off = 32; off > 0; off >>= 1)
    mx = fmaxf(mx, __shfl_down(mx, off));

  __shared__ float w[16];
  if ((threadIdx.x & 63) == 0) w[threadIdx.x >> 6] = mx;
  __syncthreads();
  if (threadIdx.x == 0) {
    float m = w[0];
#pragma unroll
    for (int i = 1; i < 16; ++i) m = fmaxf(m, w[i]);
    bdmax[bd] = m;
  }
}

// Pass 3: combine directions, sqrt, mean.
__global__ void reduce2_kernel(const float* __restrict__ bdmax,
                               float* __restrict__ out) {
  if (threadIdx.x == 0) {
    float s = 0.0f;
#pragma unroll
    for (int b = 0; b < BATCH; ++b)
      s += sqrtf(fmaxf(fmaxf(bdmax[2 * b], bdmax[2 * b + 1]), 0.0f));
    out[0] = s / (float)BATCH;
  }
}

extern "C" void kernel_launch(void* const* d_in, const int* in_sizes, int n_in,
                              void* d_out, int out_size, void* d_ws, size_t ws_size,
                              hipStream_t stream) {
  const float* x = (const float*)d_in[0];
  const float* y = (const float*)d_in[1];
  float* part  = (float*)d_ws;                       // NBD*NCHUNK*NPTS floats (4 MB)
  float* bdmax = part + (size_t)NBD * NCHUNK * NPTS; // NBD floats
  float* out = (float*)d_out;

  dim3 grid(NBLK, NCHUNK, NBD);  // (2, 16, 16) = 512 blocks
  partial_min_kernel<<<grid, BLOCK, 0, stream>>>(x, y, part);
  reduce1_kernel<<<NBD, 1024, 0, stream>>>(part, bdmax);
  reduce2_kernel<<<1, 64, 0, stream>>>(bdmax, out);
}

// Round 5
// 33.158 us; speedup vs baseline: 1.3459x; 1.3459x over previous
//
#include <hip/hip_runtime.h>
#include <math.h>

#define NPTS   4096
#define BATCH  8
#define NBD    (2 * BATCH)
#define BLOCK  256
#define PN     4                  // p points per thread
#define MCHUNK 256                // q points staged per block
#define NG     (MCHUNK / 4)       // 64 groups of 4 q points
#define NTILE  (BLOCK * PN)       // 1024 n per block
#define NBLK   (NPTS / NTILE)     // 4
#define NCHUNK (NPTS / MCHUNK)    // 16

typedef float v2f __attribute__((ext_vector_type(2)));

// Pass 1: per (bd, m-chunk, n-tile), partial min over the chunk of
// d2 = |p|^2 + (|q|^2 - 2 p.q); plain-store partials (no init, no atomics).
// bd = b*2 + dir. dir 0: p=x, q=y; dir 1: p=y, q=x.
__global__ __launch_bounds__(BLOCK) void partial_min_kernel(
    const float* __restrict__ x, const float* __restrict__ y,
    float* __restrict__ part) {
  const int bd  = blockIdx.z;
  const int b   = bd >> 1;
  const int dir = bd & 1;

  const float* __restrict__ P = (dir == 0) ? x : y;
  const float* __restrict__ Q = (dir == 0) ? y : x;
  const float* Pb = P + (size_t)b * NPTS * 3;
  const float* Qb = Q + (size_t)b * NPTS * 3 + (size_t)blockIdx.y * MCHUNK * 3;

  // Per 4-q group g: qs[g][0] = -2*qx[0..3], [1] = -2*qy, [2] = -2*qz, [3] = |q|^2
  __shared__ float4 qs[NG][4];
  if (threadIdx.x < NG) {
    const int g = threadIdx.x;
    const float4* q4 = (const float4*)(Qb + 12 * g);  // 16B-aligned (48B/group)
    const float4 A = q4[0];  // x0 y0 z0 x1
    const float4 B = q4[1];  // y1 z1 x2 y2
    const float4 C = q4[2];  // z2 x3 y3 z3
    qs[g][0] = make_float4(-2.0f * A.x, -2.0f * A.w, -2.0f * B.z, -2.0f * C.y);
    qs[g][1] = make_float4(-2.0f * A.y, -2.0f * B.x, -2.0f * B.w, -2.0f * C.z);
    qs[g][2] = make_float4(-2.0f * A.z, -2.0f * B.y, -2.0f * C.x, -2.0f * C.w);
    qs[g][3] = make_float4(A.x * A.x + A.y * A.y + A.z * A.z,
                           A.w * A.w + B.x * B.x + B.y * B.y,
                           B.z * B.z + B.w * B.w + C.x * C.x,
                           C.y * C.y + C.z * C.z + C.w * C.w);
  }
  __syncthreads();

  const int n0 = blockIdx.x * NTILE + threadIdx.x;
  v2f px2[PN], py2[PN], pz2[PN];
  float p2[PN], mn[PN];
#pragma unroll
  for (int i = 0; i < PN; ++i) {
    const int n = n0 + i * BLOCK;
    const float px = Pb[3 * n + 0];
    const float py = Pb[3 * n + 1];
    const float pz = Pb[3 * n + 2];
    px2[i] = (v2f){px, px};
    py2[i] = (v2f){py, py};
    pz2[i] = (v2f){pz, pz};
    p2[i]  = px * px + py * py + pz * pz;
    mn[i]  = 3.4e38f;
  }

#pragma unroll 2
  for (int g = 0; g < NG; ++g) {
    const float4 ax = qs[g][0];  // uniform address -> broadcast ds_read_b128
    const float4 ay = qs[g][1];
    const float4 az = qs[g][2];
    const float4 aw = qs[g][3];
    const v2f qx01 = (v2f){ax.x, ax.y}, qx23 = (v2f){ax.z, ax.w};
    const v2f qy01 = (v2f){ay.x, ay.y}, qy23 = (v2f){ay.z, ay.w};
    const v2f qz01 = (v2f){az.x, az.y}, qz23 = (v2f){az.z, az.w};
    const v2f qw01 = (v2f){aw.x, aw.y}, qw23 = (v2f){aw.z, aw.w};
#pragma unroll
    for (int i = 0; i < PN; ++i) {
      v2f t01 = __builtin_elementwise_fma(pz2[i], qz01, qw01);
      t01 = __builtin_elementwise_fma(py2[i], qy01, t01);
      t01 = __builtin_elementwise_fma(px2[i], qx01, t01);
      v2f t23 = __builtin_elementwise_fma(pz2[i], qz23, qw23);
      t23 = __builtin_elementwise_fma(py2[i], qy23, t23);
      t23 = __builtin_elementwise_fma(px2[i], qx23, t23);
      mn[i] = fminf(mn[i],
                    fminf(fminf(t01.x, t01.y), fminf(t23.x, t23.y)));
    }
  }

  float* wp = part + ((size_t)bd * NCHUNK + blockIdx.y) * NPTS + n0;
#pragma unroll
  for (int i = 0; i < PN; ++i)
    wp[i * BLOCK] = mn[i] + p2[i];
}

// Pass 2: one block per bd; min across chunks per n (coalesced), max over n.
__global__ __launch_bounds__(1024) void reduce1_kernel(
    const float* __restrict__ part, float* __restrict__ bdmax) {
  const int bd = blockIdx.x;
  const float* base = part + (size_t)bd * NCHUNK * NPTS;

  float mx = 0.0f;
  for (int n = threadIdx.x; n < NPTS; n += 1024) {
    float mn = base[n];
#pragma unroll
    for (int c = 1; c < NCHUNK; ++c)
      mn = fminf(mn, base[(size_t)c * NPTS + n]);
    mx = fmaxf(mx, mn);
  }
  for (int off = 32; off > 0; off >>= 1)
    mx = fmaxf(mx, __shfl_down(mx, off));

  __shared__ float w[16];
  if ((threadIdx.x & 63) == 0) w[threadIdx.x >> 6] = mx;
  __syncthreads();
  if (threadIdx.x == 0) {
    float m = w[0];
#pragma unroll
    for (int i = 1; i < 16; ++i) m = fmaxf(m, w[i]);
    bdmax[bd] = m;
  }
}

// Pass 3: combine directions, sqrt, mean.
__global__ void reduce2_kernel(const float* __restrict__ bdmax,
                               float* __restrict__ out) {
  if (threadIdx.x == 0) {
    float s = 0.0f;
#pragma unroll
    for (int b = 0; b < BATCH; ++b)
      s += sqrtf(fmaxf(fmaxf(bdmax[2 * b], bdmax[2 * b + 1]), 0.0f));
    out[0] = s / (float)BATCH;
  }
}

extern "C" void kernel_launch(void* const* d_in, const int* in_sizes, int n_in,
                              void* d_out, int out_size, void* d_ws, size_t ws_size,
                              hipStream_t stream) {
  const float* x = (const float*)d_in[0];
  const float* y = (const float*)d_in[1];
  float* part  = (float*)d_ws;                       // NBD*NCHUNK*NPTS floats (4 MB)
  float* bdmax = part + (size_t)NBD * NCHUNK * NPTS; // NBD floats
  float* out = (float*)d_out;

  dim3 grid(NBLK, NCHUNK, NBD);  // (4, 16, 16) = 1024 blocks
  partial_min_kernel<<<grid, BLOCK, 0, stream>>>(x, y, part);
  reduce1_kernel<<<NBD, 1024, 0, stream>>>(part, bdmax);
  reduce2_kernel<<<1, 64, 0, stream>>>(bdmax, out);
}